// Round 4
// baseline (998.533 us; speedup 1.0000x reference)
//
#include <hip/hip_runtime.h>
#include <hip/hip_bf16.h>

// B=8, T=2048, D=2048.
//   avg = cumsum(x, axis=T) / (t+1)
//   gates = concat(x, avg) @ W^T + b    (W: [4096][4096])
//   out0 = sig(gates[:, :2048]) * x + sig(gates[:, 2048:]) * avg
// outputs: [out0 fp32] ++ [avg fp32]

#define Bb 8
#define Tt 2048
#define Dd 2048
#define Mm (Bb * Tt)       // 16384
#define Kk 4096
#define NTK 128            // K-tiles of BK=32
#define NC 32
#define CT 64

typedef __bf16 bf16x8 __attribute__((ext_vector_type(8)));
typedef float f32x16 __attribute__((ext_vector_type(16)));

__device__ __forceinline__ void gload16(const void* g, void* l) {
    __builtin_amdgcn_global_load_lds(
        (const __attribute__((address_space(1))) unsigned int*)g,
        (__attribute__((address_space(3))) unsigned int*)l, 16, 0, 0);
}

// ---------------- K1: W fp32 -> bf16 ----------------
__global__ void wconv_kernel(const float* __restrict__ W,
                             unsigned short* __restrict__ Wb, long n) {
    long i = ((long)blockIdx.x * blockDim.x + threadIdx.x) * 4;
    long stride = (long)gridDim.x * blockDim.x * 4;
    for (; i < n; i += stride) {
        float4 v = *(const float4*)(W + i);
        __hip_bfloat16 a = __float2bfloat16(v.x);
        __hip_bfloat16 b = __float2bfloat16(v.y);
        __hip_bfloat16 c = __float2bfloat16(v.z);
        __hip_bfloat16 d = __float2bfloat16(v.w);
        ushort4 u;
        u.x = *(unsigned short*)&a; u.y = *(unsigned short*)&b;
        u.z = *(unsigned short*)&c; u.w = *(unsigned short*)&d;
        *(ushort4*)(Wb + i) = u;
    }
}

// ---------------- K2: per-chunk sums ----------------
__global__ void ksum_kernel(const float* __restrict__ X, float* __restrict__ S) {
    int d = blockIdx.y * 256 + threadIdx.x;
    int bc = blockIdx.x;
    int b = bc >> 5, c = bc & 31;
    const float* p = X + ((long)(b * Tt + c * CT)) * Dd + d;
    float s = 0.f;
#pragma unroll 8
    for (int t = 0; t < CT; ++t) s += p[(long)t * Dd];
    S[(long)bc * Dd + d] = s;
}

// ---------------- K3: scan + emit avg fp32 + gating_in bf16 ----------------
__global__ void kscan_kernel(const float* __restrict__ X, const float* __restrict__ S,
                             float* __restrict__ AVG, unsigned short* __restrict__ Gin) {
    int d = blockIdx.y * 256 + threadIdx.x;
    int bc = blockIdx.x;
    int b = bc >> 5, c = bc & 31;
    const float* Sp = S + (long)(b * NC) * Dd + d;
    float run = 0.f;
    for (int cc = 0; cc < c; ++cc) run += Sp[(long)cc * Dd];
    const float* p = X + ((long)(b * Tt + c * CT)) * Dd + d;
    long row = (long)b * Tt + c * CT;
    for (int tt = 0; tt < CT; ++tt) {
        float x = p[(long)tt * Dd];
        run += x;
        float av = run / (float)(c * CT + tt + 1);
        long r = row + tt;
        AVG[r * Dd + d] = av;
        __hip_bfloat16 xb = __float2bfloat16(x);
        __hip_bfloat16 ab = __float2bfloat16(av);
        Gin[r * 4096 + d] = *(unsigned short*)&xb;
        Gin[r * 4096 + 2048 + d] = *(unsigned short*)&ab;
    }
}

// ---------------- K4: 8-wave, 256 rows x 128 d (dual gate), BK=32 -----------
// mfma_f32_32x32x16_bf16. A: LDS 3-ring (3 x 16KB), staged via global_load_lds
// at distance 2, chunk-XOR swizzled (pre-swizzled global source, linear dest).
// B: registers, double-buffered, per-lane direct global_load_dwordx4 (lane la
// holds col n0+wn*32+la; 16B = 8 k-elems). One vmcnt(2)+barrier per K-tile:
// FIFO [A(t+1) x2, B(t+1) x4, A(t+2) x2] -> vmcnt(2) completes t+1's needs.
#define MFMA32(va, vb, c_) c_ = __builtin_amdgcn_mfma_f32_32x32x16_bf16(va, vb, c_, 0, 0, 0)
#define RD(p_, i_) (*(const bf16x8*)((p_) + (i_) * 2048))

#define TILE(t_, buf_, bs_, IB_, IA_, NV_)                                      \
  {                                                                             \
    if (IB_) {                                                                  \
      const long o_ = ((long)(t_) + 1) * 64;                                    \
      breg[(bs_) ^ 1][0] = *(const bf16x8*)(pB0 + o_);                          \
      breg[(bs_) ^ 1][1] = *(const bf16x8*)(pB0 + o_ + 32);                     \
      breg[(bs_) ^ 1][2] = *(const bf16x8*)(pB1 + o_);                          \
      breg[(bs_) ^ 1][3] = *(const bf16x8*)(pB1 + o_ + 32);                     \
    }                                                                           \
    if (IA_) {                                                                  \
      char* nd_ = ldsb + (((t_) + 2) % 3) * 16384 + woff;                       \
      const long ko_ = ((long)(t_) + 2) * 64;                                   \
      gload16(gA0 + ko_, nd_); gload16(gA1 + ko_, nd_ + 8192);                  \
    }                                                                           \
    {                                                                           \
      const char* pa_ = rA0 + (buf_) * 16384;                                   \
      bf16x8 a0 = RD(pa_,0), a1 = RD(pa_,1), a2 = RD(pa_,2), a3 = RD(pa_,3);    \
      __builtin_amdgcn_s_setprio(1);                                            \
      MFMA32(a0, breg[bs_][0], acc[0][0]); MFMA32(a0, breg[bs_][2], acc[0][1]); \
      MFMA32(a1, breg[bs_][0], acc[1][0]); MFMA32(a1, breg[bs_][2], acc[1][1]); \
      MFMA32(a2, breg[bs_][0], acc[2][0]); MFMA32(a2, breg[bs_][2], acc[2][1]); \
      MFMA32(a3, breg[bs_][0], acc[3][0]); MFMA32(a3, breg[bs_][2], acc[3][1]); \
      __builtin_amdgcn_s_setprio(0);                                            \
    }                                                                           \
    {                                                                           \
      const char* pa_ = rA1 + (buf_) * 16384;                                   \
      bf16x8 a0 = RD(pa_,0), a1 = RD(pa_,1), a2 = RD(pa_,2), a3 = RD(pa_,3);    \
      __builtin_amdgcn_s_setprio(1);                                            \
      MFMA32(a0, breg[bs_][1], acc[0][0]); MFMA32(a0, breg[bs_][3], acc[0][1]); \
      MFMA32(a1, breg[bs_][1], acc[1][0]); MFMA32(a1, breg[bs_][3], acc[1][1]); \
      MFMA32(a2, breg[bs_][1], acc[2][0]); MFMA32(a2, breg[bs_][3], acc[2][1]); \
      MFMA32(a3, breg[bs_][1], acc[3][0]); MFMA32(a3, breg[bs_][3], acc[3][1]); \
      __builtin_amdgcn_s_setprio(0);                                            \
    }                                                                           \
    asm volatile("s_waitcnt vmcnt(" #NV_ ")" ::: "memory");                     \
    __builtin_amdgcn_s_barrier();                                               \
    __builtin_amdgcn_sched_barrier(0);                                          \
  }

__global__ __launch_bounds__(512, 2) void gemm32r_kernel(
    const unsigned short* __restrict__ Gin,  // [16384][4096] bf16
    const unsigned short* __restrict__ Wb,   // [4096][4096] bf16
    const float* __restrict__ bias,          // [4096]
    const float* __restrict__ X,             // [16384][2048]
    const float* __restrict__ AVG,           // [16384][2048]
    float* __restrict__ OUT)                 // [16384][2048]
{
    __shared__ __attribute__((aligned(128))) char lds[49152]; // 3 x 16KB (A only)
    char* ldsb = (char*)lds;

    const int tid = threadIdx.x;
    const int w = tid >> 6, l = tid & 63;
    const int wm = w >> 2, wn = w & 3;       // 2(M) x 4(N) waves
    const int la = l & 31;
    const int lk = l >> 5;
    const int woff = w * 1024;

    // Batch-aware mapping: 256-block rounds = 16 m-tiles x 16 n-tiles (L3);
    // per XCD: 2 n-tiles (B panel 2MB -> L2-resident).
    const int bid = blockIdx.x;
    const int batch = bid >> 8;
    const int rr = bid & 255;
    const int xcd = rr & 7;
    const int j = rr >> 3;
    const int nt = xcd * 2 + (j >> 4);
    const int mt = batch * 16 + (j & 15);
    const long m0 = (long)mt * 256;
    const int n0 = nt * 128;

    // ---- A staging (pre-swizzled global chunk; LDS dest linear) ----
    const int srow = tid >> 2;
    const int schunk = (tid & 3) ^ ((tid >> 3) & 3);
    const char* gA0 = (const char*)Gin + (m0 + srow) * 8192 + schunk * 16;
    const char* gA1 = gA0 + 128 * 8192;

    // ---- B register-load bases: lane la = column d-offset ----
    const char* pB0 = (const char*)Wb + (long)(n0 + wn * 32 + la) * 8192 + lk * 16;
    const char* pB1 = (const char*)Wb + (long)(n0 + wn * 32 + la + 2048) * 8192 + lk * 16;

    // ---- A read addresses (swizzled chunk) ----
    const int cb0 = ((lk ^ ((la >> 1) & 3))) * 16;      // kk=0
    const int cb1 = cb0 ^ 32;                           // kk=1
    const char* rA0 = ldsb + (wm * 128 + la) * 64 + cb0;   // + buf*16384 + mi*2048
    const char* rA1 = ldsb + (wm * 128 + la) * 64 + cb1;

    f32x16 acc[4][2] = {};    // [mi][ni]; ni=0 input gate, ni=1 forget gate
    bf16x8 breg[2][4];        // [set][ni*2+kk]

    // prologue: stage A tiles 0,1; load B tile 0
    gload16(gA0,      ldsb + woff);
    gload16(gA1,      ldsb + 8192 + woff);
    gload16(gA0 + 64, ldsb + 16384 + woff);
    gload16(gA1 + 64, ldsb + 16384 + 8192 + woff);
    breg[0][0] = *(const bf16x8*)(pB0);
    breg[0][1] = *(const bf16x8*)(pB0 + 32);
    breg[0][2] = *(const bf16x8*)(pB1);
    breg[0][3] = *(const bf16x8*)(pB1 + 32);
    asm volatile("s_waitcnt vmcnt(0)" ::: "memory");
    __builtin_amdgcn_s_barrier();
    __builtin_amdgcn_sched_barrier(0);

#pragma unroll 1
    for (int t = 0; t < 126; t += 6) {
        TILE(t + 0, 0, 0, 1, 1, 2)
        TILE(t + 1, 1, 1, 1, 1, 2)
        TILE(t + 2, 2, 0, 1, 1, 2)
        TILE(t + 3, 0, 1, 1, 1, 2)
        TILE(t + 4, 1, 0, 1, 1, 2)
        TILE(t + 5, 2, 1, 1, 1, 2)
    }
    TILE(126, 0, 0, 1, 0, 0)
    TILE(127, 1, 1, 0, 0, 0)

    // ---- fused epilogue ----
    // C/D (32x32): col = lane&31, row = (q&3) + 8*(q>>2) + 4*(lane>>5)
    const int d = n0 + wn * 32 + la;
    const float bi_ = bias[d];
    const float bf_ = bias[d + 2048];
#pragma unroll
    for (int mi = 0; mi < 4; ++mi) {
        const long rb = m0 + wm * 128 + mi * 32 + lk * 4;
        f32x16 ci = acc[mi][0];
        f32x16 cf = acc[mi][1];
#pragma unroll
        for (int q = 0; q < 16; ++q) {
            long row = rb + (q & 3) + 8 * (q >> 2);
            long idx = row * 2048 + d;
            float gi = ci[q] + bi_;
            float gf = cf[q] + bf_;
            float x = X[idx];
            float av = AVG[idx];
            float si = 1.f / (1.f + __expf(-gi));
            float sf = 1.f / (1.f + __expf(-gf));
            OUT[idx] = si * x + sf * av;
        }
    }
}

extern "C" void kernel_launch(void* const* d_in, const int* in_sizes, int n_in,
                              void* d_out, int out_size, void* d_ws, size_t ws_size,
                              hipStream_t stream) {
    const float* X = (const float*)d_in[0];     // layer_in [8][2048][2048]
    const float* W = (const float*)d_in[1];     // W_gate [4096][4096]
    const float* bias = (const float*)d_in[2];  // b_gate [4096]

    float* OUT = (float*)d_out;                 // gating_out
    float* AVG = OUT + (long)Mm * Dd;           // average_out

    char* ws = (char*)d_ws;
    unsigned short* Wb  = (unsigned short*)ws;                    // 33,554,432 B
    unsigned short* Gin = (unsigned short*)(ws + 33554432);       // 134,217,728 B
    float* S = (float*)(ws + 33554432 + 134217728);               // 2,097,152 B

    wconv_kernel<<<2048, 256, 0, stream>>>(W, Wb, (long)Kk * Kk);
    ksum_kernel<<<dim3(Bb * NC, Dd / 256), 256, 0, stream>>>(X, S);
    kscan_kernel<<<dim3(Bb * NC, Dd / 256), 256, 0, stream>>>(X, S, AVG, Gin);
    gemm32r_kernel<<<1024, 512, 0, stream>>>(Gin, Wb, bias, X, AVG, OUT);
}

// Round 5
// 775.067 us; speedup vs baseline: 1.2883x; 1.2883x over previous
//
#include <hip/hip_runtime.h>
#include <hip/hip_bf16.h>

// B=8, T=2048, D=2048.
//   avg = cumsum(x, axis=T) / (t+1)
//   gates = concat(x, avg) @ W^T + b    (W: [4096][4096])
//   out0 = sig(gates[:, :2048]) * x + sig(gates[:, 2048:]) * avg
// outputs: [out0 fp32] ++ [avg fp32]

#define Bb 8
#define Tt 2048
#define Dd 2048
#define Mm (Bb * Tt)       // 16384
#define Kk 4096
#define NC 32
#define CT 64

typedef __bf16 bf16x8 __attribute__((ext_vector_type(8)));
typedef float f32x4 __attribute__((ext_vector_type(4)));

__device__ __forceinline__ void gload16(const void* g, void* l) {
    __builtin_amdgcn_global_load_lds(
        (const __attribute__((address_space(1))) unsigned int*)g,
        (__attribute__((address_space(3))) unsigned int*)l, 16, 0, 0);
}

// ---------------- K1: W fp32 -> bf16 ----------------
__global__ void wconv_kernel(const float* __restrict__ W,
                             unsigned short* __restrict__ Wb, long n) {
    long i = ((long)blockIdx.x * blockDim.x + threadIdx.x) * 4;
    long stride = (long)gridDim.x * blockDim.x * 4;
    for (; i < n; i += stride) {
        float4 v = *(const float4*)(W + i);
        __hip_bfloat16 a = __float2bfloat16(v.x);
        __hip_bfloat16 b = __float2bfloat16(v.y);
        __hip_bfloat16 c = __float2bfloat16(v.z);
        __hip_bfloat16 d = __float2bfloat16(v.w);
        ushort4 u;
        u.x = *(unsigned short*)&a; u.y = *(unsigned short*)&b;
        u.z = *(unsigned short*)&c; u.w = *(unsigned short*)&d;
        *(ushort4*)(Wb + i) = u;
    }
}

// ---------------- K2: per-chunk sums ----------------
__global__ void ksum_kernel(const float* __restrict__ X, float* __restrict__ S) {
    int d = blockIdx.y * 256 + threadIdx.x;
    int bc = blockIdx.x;
    int b = bc >> 5, c = bc & 31;
    const float* p = X + ((long)(b * Tt + c * CT)) * Dd + d;
    float s = 0.f;
#pragma unroll 8
    for (int t = 0; t < CT; ++t) s += p[(long)t * Dd];
    S[(long)bc * Dd + d] = s;
}

// ---------------- K3: scan + emit avg fp32 + gating_in bf16 ----------------
__global__ void kscan_kernel(const float* __restrict__ X, const float* __restrict__ S,
                             float* __restrict__ AVG, unsigned short* __restrict__ Gin) {
    int d = blockIdx.y * 256 + threadIdx.x;
    int bc = blockIdx.x;
    int b = bc >> 5, c = bc & 31;
    const float* Sp = S + (long)(b * NC) * Dd + d;
    float run = 0.f;
    for (int cc = 0; cc < c; ++cc) run += Sp[(long)cc * Dd];
    const float* p = X + ((long)(b * Tt + c * CT)) * Dd + d;
    long row = (long)b * Tt + c * CT;
    for (int tt = 0; tt < CT; ++tt) {
        float x = p[(long)tt * Dd];
        run += x;
        float av = run / (float)(c * CT + tt + 1);
        long r = row + tt;
        AVG[r * Dd + d] = av;
        __hip_bfloat16 xb = __float2bfloat16(x);
        __hip_bfloat16 ab = __float2bfloat16(av);
        Gin[r * 4096 + d] = *(unsigned short*)&xb;
        Gin[r * 4096 + 2048 + d] = *(unsigned short*)&ab;
    }
}

// ---------------- K4: 8-wave 256x(128d x 2 gates), BK=32, 4-phase tiles -----
// 16x16x32 MFMA (R2's proven 0-conflict swizzle). 2-deep LDS ring (2 x 32KB):
// reads for tile t+1 are register-pipelined during tile t (phases 3,4), so
// buf[t] is never re-read during tile t and stages for t+2 can target
// buf[t%2]. One counted vmcnt(4) per tile (phase-2 end). 3-rotating register
// sets (A,B,C), static via unroll-6. 8 barriers/tile create the phase-split
// that makes T2 (swizzle) and T5 (setprio) active per the regime gate.
#define MFMA(va, vb, c_) c_ = __builtin_amdgcn_mfma_f32_16x16x32_bf16(va, vb, c_, 0, 0, 0)

#define RDSET_RG0(S_, obb_)                                               \
  a##S_##0 = *(const bf16x8*)(rA0 + (obb_));                              \
  a##S_##1 = *(const bf16x8*)(rA0 + (obb_) + 1024);                       \
  a##S_##2 = *(const bf16x8*)(rA0 + (obb_) + 2048);                       \
  a##S_##3 = *(const bf16x8*)(rA0 + (obb_) + 3072);                       \
  b##S_##0 = *(const bf16x8*)(rB0 + (obb_));                              \
  b##S_##1 = *(const bf16x8*)(rB0 + (obb_) + 1024);

#define RDSET_RG1(S_, obb_)                                               \
  a##S_##0 = *(const bf16x8*)(rA0 + (obb_) + 4096);                       \
  a##S_##1 = *(const bf16x8*)(rA0 + (obb_) + 5120);                       \
  a##S_##2 = *(const bf16x8*)(rA0 + (obb_) + 6144);                       \
  a##S_##3 = *(const bf16x8*)(rA0 + (obb_) + 7168);                       \
  b##S_##0 = *(const bf16x8*)(rB0 + (obb_) + 2048);                       \
  b##S_##1 = *(const bf16x8*)(rB0 + (obb_) + 3072);

// RG0 set = A rows 0-63 + gate-i B frags; RG1 set = A rows 64-127 + gate-f.
#define CL_M0(S_)                                                         \
  MFMA(a##S_##0, b##S_##0, acc[0][0]); MFMA(a##S_##0, b##S_##1, acc[0][1]);\
  MFMA(a##S_##1, b##S_##0, acc[1][0]); MFMA(a##S_##1, b##S_##1, acc[1][1]);\
  MFMA(a##S_##2, b##S_##0, acc[2][0]); MFMA(a##S_##2, b##S_##1, acc[2][1]);\
  MFMA(a##S_##3, b##S_##0, acc[3][0]); MFMA(a##S_##3, b##S_##1, acc[3][1]);
#define CL_M1(SA_, SB_)                                                   \
  MFMA(a##SA_##0, b##SB_##0, acc[0][2]); MFMA(a##SA_##0, b##SB_##1, acc[0][3]);\
  MFMA(a##SA_##1, b##SB_##0, acc[1][2]); MFMA(a##SA_##1, b##SB_##1, acc[1][3]);\
  MFMA(a##SA_##2, b##SB_##0, acc[2][2]); MFMA(a##SA_##2, b##SB_##1, acc[2][3]);\
  MFMA(a##SA_##3, b##SB_##0, acc[3][2]); MFMA(a##SA_##3, b##SB_##1, acc[3][3]);
#define CL_M2(SB_, SA_)                                                   \
  MFMA(a##SB_##0, b##SA_##0, acc[4][0]); MFMA(a##SB_##0, b##SA_##1, acc[4][1]);\
  MFMA(a##SB_##1, b##SA_##0, acc[5][0]); MFMA(a##SB_##1, b##SA_##1, acc[5][1]);\
  MFMA(a##SB_##2, b##SA_##0, acc[6][0]); MFMA(a##SB_##2, b##SA_##1, acc[6][1]);\
  MFMA(a##SB_##3, b##SA_##0, acc[7][0]); MFMA(a##SB_##3, b##SA_##1, acc[7][1]);
#define CL_M3(SB_)                                                        \
  MFMA(a##SB_##0, b##SB_##0, acc[4][2]); MFMA(a##SB_##0, b##SB_##1, acc[4][3]);\
  MFMA(a##SB_##1, b##SB_##0, acc[5][2]); MFMA(a##SB_##1, b##SB_##1, acc[5][3]);\
  MFMA(a##SB_##2, b##SB_##0, acc[6][2]); MFMA(a##SB_##2, b##SB_##1, acc[6][3]);\
  MFMA(a##SB_##3, b##SB_##0, acc[7][2]); MFMA(a##SB_##3, b##SB_##1, acc[7][3]);

#define SBAR __builtin_amdgcn_s_barrier()
#define SCHB __builtin_amdgcn_sched_barrier(0)

#define TILE(t_, bb_, CA_, CB_, NX_, STG_, VN_, RDS_)                     \
  {                                                                       \
    /* PH1: stage A(t+2) -> buf[t%2]; M0 */                               \
    if (STG_) { const long ko_ = ((long)(t_) + 2) * 64;                   \
      gload16(gA0 + ko_, ldsb + (bb_) + woff);                            \
      gload16(gA1 + ko_, ldsb + (bb_) + 8192 + woff); }                   \
    SCHB; SBAR; SCHB;                                                     \
    __builtin_amdgcn_s_setprio(1); CL_M0(CA_); __builtin_amdgcn_s_setprio(0); \
    SCHB; SBAR;                                                           \
    /* PH2: stage B(t+2); M1; counted vmcnt -> t+1 staged everywhere */   \
    if (STG_) { const long ko_ = ((long)(t_) + 2) * 64;                   \
      gload16(gB0 + ko_, ldsb + (bb_) + 16384 + woff);                    \
      gload16(gB1 + ko_, ldsb + (bb_) + 24576 + woff); }                  \
    SCHB; SBAR; SCHB;                                                     \
    __builtin_amdgcn_s_setprio(1); CL_M1(CA_, CB_); __builtin_amdgcn_s_setprio(0); \
    SCHB;                                                                 \
    asm volatile("s_waitcnt vmcnt(" #VN_ ")" ::: "memory");               \
    SBAR;                                                                 \
    /* PH3: read RG0(t+1) from other buf; M2 */                           \
    if (RDS_) { RDSET_RG0(NX_, (bb_) ^ 32768); }                          \
    SCHB; SBAR; SCHB;                                                     \
    __builtin_amdgcn_s_setprio(1); CL_M2(CB_, CA_); __builtin_amdgcn_s_setprio(0); \
    SCHB; SBAR;                                                           \
    /* PH4: read RG1(t+1); M3 */                                          \
    if (RDS_) { RDSET_RG1(CA_, (bb_) ^ 32768); }                          \
    SCHB; SBAR; SCHB;                                                     \
    __builtin_amdgcn_s_setprio(1); CL_M3(CB_); __builtin_amdgcn_s_setprio(0); \
    SCHB; SBAR;                                                           \
  }

__global__ __launch_bounds__(512, 2) void gemm4p_kernel(
    const unsigned short* __restrict__ Gin,  // [16384][4096] bf16
    const unsigned short* __restrict__ Wb,   // [4096][4096] bf16
    const float* __restrict__ bias,          // [4096]
    float* __restrict__ OUT)                 // [16384][2048]
{
    __shared__ __attribute__((aligned(128))) char lds[65536]; // 2 x (A16K + B16K)
    char* ldsb = (char*)lds;

    const int tid = threadIdx.x;
    const int w = tid >> 6, l = tid & 63;
    const int wm = w >> 2, wn = w & 3;       // 2(M) x 4(N) waves
    const int lm = l & 15;
    const int woff = w * 1024;

    // Batch-aware mapping (R3, FETCH-proven): 256-block rounds = 16 m-tiles x
    // 16 n-tiles (A 32MB + W 32MB < L3); per XCD 2 n-tiles (B panel -> L2).
    const int bid = blockIdx.x;
    const int batch = bid >> 8;
    const int rr = bid & 255;
    const int xcd = rr & 7;
    const int j = rr >> 3;
    const int nt = xcd * 2 + (j >> 4);
    const int mt = batch * 16 + (j & 15);
    const long m0 = (long)mt * 256;
    const int n0 = nt * 128;

    // ---- staging addresses (pre-swizzled global chunk; LDS dest linear) ----
    const int srow = tid >> 2;
    const int schunk = (tid & 3) ^ ((tid >> 3) & 3);
    const char* gA0 = (const char*)Gin + (m0 + srow) * 8192 + schunk * 16;
    const char* gA1 = gA0 + 128 * 8192;
    // B tile row j (0..255) -> W row: d-block (j>>6)*32 + (j&31), gate (j>>5)&1
    const long jr0 = n0 + ((srow >> 6) << 5) + (srow & 31) + (((srow >> 5) & 1) << 11);
    const int j1 = 128 + srow;
    const long jr1 = n0 + ((j1 >> 6) << 5) + (j1 & 31) + (((j1 >> 5) & 1) << 11);
    const char* gB0 = (const char*)Wb + jr0 * 8192 + schunk * 16;
    const char* gB1 = (const char*)Wb + jr1 * 8192 + schunk * 16;

    // ---- read addresses (R2's proven swizzle: full-row chunk coverage) ----
    const int cbyte = (((l >> 4) ^ ((lm >> 1) & 3))) * 16;
    const char* rA0 = ldsb + (wm * 128 + lm) * 64 + cbyte;          // +obb +i*1024
    const char* rB0 = ldsb + 16384 + (wn * 64 + lm) * 64 + cbyte;   // +obb +j*1024

    f32x4 acc[8][4] = {};   // [mi][bj]: bj 0-1 gate-i, 2-3 gate-f

    // 3 rotating operand sets
    bf16x8 aA0{}, aA1{}, aA2{}, aA3{}, bA0{}, bA1{};
    bf16x8 aB0{}, aB1{}, aB2{}, aB3{}, bB0{}, bB1{};
    bf16x8 aC0{}, aC1{}, aC2{}, aC3{}, bC0{}, bC1{};

    // prologue: stage tiles 0 (buf0) and 1 (buf1); read tile-0 operand sets
    gload16(gA0,      ldsb + woff);
    gload16(gA1,      ldsb + 8192 + woff);
    gload16(gB0,      ldsb + 16384 + woff);
    gload16(gB1,      ldsb + 24576 + woff);
    gload16(gA0 + 64, ldsb + 32768 + woff);
    gload16(gA1 + 64, ldsb + 32768 + 8192 + woff);
    gload16(gB0 + 64, ldsb + 32768 + 16384 + woff);
    gload16(gB1 + 64, ldsb + 32768 + 24576 + woff);
    asm volatile("s_waitcnt vmcnt(4)" ::: "memory");   // tile 0 landed
    SBAR; SCHB;
    RDSET_RG0(A, 0); RDSET_RG1(B, 0);
    SCHB; SBAR;   // seal buf0 reads before t=0 PH1 stages buf0

#pragma unroll 1
    for (int t = 0; t < 126; t += 6) {
        TILE(t + 0, 0,     A, B, C, 1, 4, 1)
        TILE(t + 1, 32768, C, A, B, 1, 4, 1)
        TILE(t + 2, 0,     B, C, A, 1, 4, 1)
        TILE(t + 3, 32768, A, B, C, 1, 4, 1)
        TILE(t + 4, 0,     C, A, B, 1, 4, 1)
        TILE(t + 5, 32768, B, C, A, 1, 4, 1)
    }
    TILE(126, 0,     A, B, C, 0, 0, 1)
    TILE(127, 32768, C, A, B, 0, 0, 0)

    // ---- fused epilogue (bf16 x/avg from Gin; C/D: col=l&15, row=(l>>4)*4+r)
#pragma unroll
    for (int mi = 0; mi < 8; ++mi) {
        long rbase = m0 + wm * 128 + mi * 16 + (l >> 4) * 4;
#pragma unroll
        for (int nj = 0; nj < 2; ++nj) {
            int d = n0 + wn * 32 + nj * 16 + lm;
            float bi_ = bias[d];
            float bf_ = bias[d + 2048];
#pragma unroll
            for (int r = 0; r < 4; ++r) {
                long row = rbase + r;
                unsigned int ux = Gin[row * 4096 + d];
                unsigned int ua = Gin[row * 4096 + 2048 + d];
                union { unsigned int u; float f; } cx, ca;
                cx.u = ux << 16; ca.u = ua << 16;
                float gi = acc[mi][nj][r] + bi_;
                float gf = acc[mi][nj + 2][r] + bf_;
                float si = 1.f / (1.f + __expf(-gi));
                float sf = 1.f / (1.f + __expf(-gf));
                OUT[row * 2048 + d] = si * cx.f + sf * ca.f;
            }
        }
    }
}

extern "C" void kernel_launch(void* const* d_in, const int* in_sizes, int n_in,
                              void* d_out, int out_size, void* d_ws, size_t ws_size,
                              hipStream_t stream) {
    const float* X = (const float*)d_in[0];     // layer_in [8][2048][2048]
    const float* W = (const float*)d_in[1];     // W_gate [4096][4096]
    const float* bias = (const float*)d_in[2];  // b_gate [4096]

    float* OUT = (float*)d_out;                 // gating_out
    float* AVG = OUT + (long)Mm * Dd;           // average_out

    char* ws = (char*)d_ws;
    unsigned short* Wb  = (unsigned short*)ws;                    // 33,554,432 B
    unsigned short* Gin = (unsigned short*)(ws + 33554432);       // 134,217,728 B
    float* S = (float*)(ws + 33554432 + 134217728);               // 2,097,152 B

    wconv_kernel<<<2048, 256, 0, stream>>>(W, Wb, (long)Kk * Kk);
    ksum_kernel<<<dim3(Bb * NC, Dd / 256), 256, 0, stream>>>(X, S);
    kscan_kernel<<<dim3(Bb * NC, Dd / 256), 256, 0, stream>>>(X, S, AVG, Gin);
    gemm4p_kernel<<<1024, 512, 0, stream>>>(Gin, Wb, bias, OUT);
}

// Round 6
// 634.749 us; speedup vs baseline: 1.5731x; 1.2211x over previous
//
#include <hip/hip_runtime.h>
#include <hip/hip_bf16.h>

// B=8, T=2048, D=2048.
//   avg = cumsum(x, axis=T) / (t+1)
//   gates = concat(x, avg) @ W^T + b    (W: [4096][4096])
//   out0 = sig(gates[:, :2048]) * x + sig(gates[:, 2048:]) * avg
// outputs: [out0 fp32] ++ [avg fp32]

#define Bb 8
#define Tt 2048
#define Dd 2048
#define Mm (Bb * Tt)       // 16384
#define Kk 4096
#define NC 32
#define CT 64

typedef __bf16 bf16x8 __attribute__((ext_vector_type(8)));
typedef float f32x4 __attribute__((ext_vector_type(4)));

__device__ __forceinline__ void gload16(const void* g, void* l) {
    __builtin_amdgcn_global_load_lds(
        (const __attribute__((address_space(1))) unsigned int*)g,
        (__attribute__((address_space(3))) unsigned int*)l, 16, 0, 0);
}

// ---------------- K1: W fp32 -> bf16 ----------------
__global__ void wconv_kernel(const float* __restrict__ W,
                             unsigned short* __restrict__ Wb, long n) {
    long i = ((long)blockIdx.x * blockDim.x + threadIdx.x) * 4;
    long stride = (long)gridDim.x * blockDim.x * 4;
    for (; i < n; i += stride) {
        float4 v = *(const float4*)(W + i);
        __hip_bfloat16 a = __float2bfloat16(v.x);
        __hip_bfloat16 b = __float2bfloat16(v.y);
        __hip_bfloat16 c = __float2bfloat16(v.z);
        __hip_bfloat16 d = __float2bfloat16(v.w);
        ushort4 u;
        u.x = *(unsigned short*)&a; u.y = *(unsigned short*)&b;
        u.z = *(unsigned short*)&c; u.w = *(unsigned short*)&d;
        *(ushort4*)(Wb + i) = u;
    }
}

// ---------------- K2: per-chunk sums ----------------
__global__ void ksum_kernel(const float* __restrict__ X, float* __restrict__ S) {
    int d = blockIdx.y * 256 + threadIdx.x;
    int bc = blockIdx.x;
    int b = bc >> 5, c = bc & 31;
    const float* p = X + ((long)(b * Tt + c * CT)) * Dd + d;
    float s = 0.f;
#pragma unroll 8
    for (int t = 0; t < CT; ++t) s += p[(long)t * Dd];
    S[(long)bc * Dd + d] = s;
}

// ---------------- K3: scan + emit avg fp32 + gating_in bf16 ----------------
__global__ void kscan_kernel(const float* __restrict__ X, const float* __restrict__ S,
                             float* __restrict__ AVG, unsigned short* __restrict__ Gin) {
    int d = blockIdx.y * 256 + threadIdx.x;
    int bc = blockIdx.x;
    int b = bc >> 5, c = bc & 31;
    const float* Sp = S + (long)(b * NC) * Dd + d;
    float run = 0.f;
    for (int cc = 0; cc < c; ++cc) run += Sp[(long)cc * Dd];
    const float* p = X + ((long)(b * Tt + c * CT)) * Dd + d;
    long row = (long)b * Tt + c * CT;
    for (int tt = 0; tt < CT; ++tt) {
        float x = p[(long)tt * Dd];
        run += x;
        float av = run / (float)(c * CT + tt + 1);
        long r = row + tt;
        AVG[r * Dd + d] = av;
        __hip_bfloat16 xb = __float2bfloat16(x);
        __hip_bfloat16 ab = __float2bfloat16(av);
        Gin[r * 4096 + d] = *(unsigned short*)&xb;
        Gin[r * 4096 + 2048 + d] = *(unsigned short*)&ab;
    }
}

// ---------------- K4: 8-wave 256x(128d x 2 gates), BK=32, m201-phase body ---
// R2's proven frame: 4-deep LDS ring (4 x 32KB), distance-3 staging via
// global_load_lds (pre-swizzled global source, linear dest), counted vmcnt(8)
// boundary (never 0 in loop), 0-conflict chunk-XOR swizzle on reads.
// New: per half-tile m201 phase discipline —
//   {ds_reads + stage ; s_barrier ; lgkmcnt(0)+sched_barrier ;
//    setprio(1) 16xMFMA setprio(0) ; s_barrier}
// 4 barriers/K-tile total (template rate), 16-MFMA clusters.
#define MFMA(va, vb, c_) c_ = __builtin_amdgcn_mfma_f32_16x16x32_bf16(va, vb, c_, 0, 0, 0)
#define RD(p_, i_) (*(const bf16x8*)((p_) + (i_) * 1024))
#define SBAR __builtin_amdgcn_s_barrier()
#define SCHB __builtin_amdgcn_sched_barrier(0)

#define TILEBODY(t_, STG_)                                                      \
  {                                                                             \
    const int buf_ = (t_) & 3;                                                  \
    const char* pa_ = rA0 + buf_ * 32768;                                       \
    const char* pb_ = rB0 + buf_ * 32768;                                       \
    /* ---- phase 0: reads A0-3,B0-3; stage A(t+3); MFMA mi0-3 ---- */          \
    bf16x8 a0 = RD(pa_,0), a1 = RD(pa_,1), a2 = RD(pa_,2), a3 = RD(pa_,3);      \
    bf16x8 b0 = RD(pb_,0), b1 = RD(pb_,1), b2 = RD(pb_,2), b3 = RD(pb_,3);      \
    if (STG_) { char* nd_ = ldsb + (((t_) + 3) & 3) * 32768 + woff;             \
      const long ko_ = ((long)(t_) + 3) * 64;                                   \
      gload16(gA0 + ko_, nd_); gload16(gA1 + ko_, nd_ + 8192); }                \
    SCHB; SBAR;                                                                 \
    asm volatile("s_waitcnt lgkmcnt(0)" ::: "memory"); SCHB;                    \
    __builtin_amdgcn_s_setprio(1);                                              \
    MFMA(a0,b0,acc[0][0]); MFMA(a0,b1,acc[0][1]); MFMA(a0,b2,acc[0][2]); MFMA(a0,b3,acc[0][3]); \
    MFMA(a1,b0,acc[1][0]); MFMA(a1,b1,acc[1][1]); MFMA(a1,b2,acc[1][2]); MFMA(a1,b3,acc[1][3]); \
    MFMA(a2,b0,acc[2][0]); MFMA(a2,b1,acc[2][1]); MFMA(a2,b2,acc[2][2]); MFMA(a2,b3,acc[2][3]); \
    MFMA(a3,b0,acc[3][0]); MFMA(a3,b1,acc[3][1]); MFMA(a3,b2,acc[3][2]); MFMA(a3,b3,acc[3][3]); \
    __builtin_amdgcn_s_setprio(0); SCHB; SBAR;                                  \
    /* ---- phase 1: reads A4-7; stage B(t+3); MFMA mi4-7 ---- */               \
    bf16x8 a4 = RD(pa_,4), a5 = RD(pa_,5), a6 = RD(pa_,6), a7 = RD(pa_,7);      \
    if (STG_) { char* nd_ = ldsb + (((t_) + 3) & 3) * 32768 + 16384 + woff;     \
      const long ko_ = ((long)(t_) + 3) * 64;                                   \
      gload16(gB0 + ko_, nd_); gload16(gB1 + ko_, nd_ + 8192); }                \
    SCHB; SBAR;                                                                 \
    asm volatile("s_waitcnt lgkmcnt(0)" ::: "memory"); SCHB;                    \
    __builtin_amdgcn_s_setprio(1);                                              \
    MFMA(a4,b0,acc[4][0]); MFMA(a4,b1,acc[4][1]); MFMA(a4,b2,acc[4][2]); MFMA(a4,b3,acc[4][3]); \
    MFMA(a5,b0,acc[5][0]); MFMA(a5,b1,acc[5][1]); MFMA(a5,b2,acc[5][2]); MFMA(a5,b3,acc[5][3]); \
    MFMA(a6,b0,acc[6][0]); MFMA(a6,b1,acc[6][1]); MFMA(a6,b2,acc[6][2]); MFMA(a6,b3,acc[6][3]); \
    MFMA(a7,b0,acc[7][0]); MFMA(a7,b1,acc[7][1]); MFMA(a7,b2,acc[7][2]); MFMA(a7,b3,acc[7][3]); \
    __builtin_amdgcn_s_setprio(0); SCHB;                                        \
  }

#define BOUNDARY(N_)                                                            \
  asm volatile("s_waitcnt vmcnt(" #N_ ")" ::: "memory");                        \
  SBAR; SCHB;

__global__ __launch_bounds__(512, 1) void gemm2p_kernel(
    const unsigned short* __restrict__ Gin,  // [16384][4096] bf16
    const unsigned short* __restrict__ Wb,   // [4096][4096] bf16
    const float* __restrict__ bias,          // [4096]
    float* __restrict__ OUT)                 // [16384][2048]
{
    __shared__ __attribute__((aligned(128))) char lds[131072]; // 4 x (A16K+B16K)
    char* ldsb = (char*)lds;

    const int tid = threadIdx.x;
    const int w = tid >> 6, l = tid & 63;
    const int wm = w >> 2, wn = w & 3;       // 2(M) x 4(N) waves
    const int lm = l & 15;
    const int woff = w * 1024;

    // Batch-aware mapping (R3, FETCH-proven): 256-block rounds = 16 m-tiles x
    // 16 n-tiles (A 32MB + W 32MB < L3); per XCD 2 n-tiles (B panel -> L2).
    const int bid = blockIdx.x;
    const int batch = bid >> 8;
    const int rr = bid & 255;
    const int xcd = rr & 7;
    const int j = rr >> 3;
    const int nt = xcd * 2 + (j >> 4);
    const int mt = batch * 16 + (j & 15);
    const long m0 = (long)mt * 256;
    const int n0 = nt * 128;

    // ---- staging addresses (pre-swizzled global chunk; LDS dest linear) ----
    const int srow = tid >> 2;
    const int schunk = (tid & 3) ^ ((tid >> 3) & 3);
    const char* gA0 = (const char*)Gin + (m0 + srow) * 8192 + schunk * 16;
    const char* gA1 = gA0 + 128 * 8192;
    // B tile row j (0..255) -> W row: d-block (j>>6)*32 + (j&31), gate (j>>5)&1
    const long jr0 = n0 + ((srow >> 6) << 5) + (srow & 31) + (((srow >> 5) & 1) << 11);
    const int j1 = 128 + srow;
    const long jr1 = n0 + ((j1 >> 6) << 5) + (j1 & 31) + (((j1 >> 5) & 1) << 11);
    const char* gB0 = (const char*)Wb + jr0 * 8192 + schunk * 16;
    const char* gB1 = (const char*)Wb + jr1 * 8192 + schunk * 16;

    // ---- read addresses (R2's proven 0-conflict swizzle) ----
    const int cbyte = (((l >> 4) ^ ((lm >> 1) & 3))) * 16;
    const char* rA0 = ldsb + (wm * 128 + lm) * 64 + cbyte;          // +buf +mi*1024
    const char* rB0 = ldsb + 16384 + (wn * 64 + lm) * 64 + cbyte;   // +buf +nj*1024

    f32x4 acc[8][4] = {};   // [mi][nj]: nj 0-1 gate-i, 2-3 gate-f

    // prologue: stage tiles 0,1,2 (per tile: A0,A1,B0,B1 — matches loop order)
    {
        gload16(gA0,       ldsb + woff);
        gload16(gA1,       ldsb + 8192 + woff);
        gload16(gB0,       ldsb + 16384 + woff);
        gload16(gB1,       ldsb + 24576 + woff);
        gload16(gA0 + 64,  ldsb + 32768 + woff);
        gload16(gA1 + 64,  ldsb + 32768 + 8192 + woff);
        gload16(gB0 + 64,  ldsb + 32768 + 16384 + woff);
        gload16(gB1 + 64,  ldsb + 32768 + 24576 + woff);
        gload16(gA0 + 128, ldsb + 65536 + woff);
        gload16(gA1 + 128, ldsb + 65536 + 8192 + woff);
        gload16(gB0 + 128, ldsb + 65536 + 16384 + woff);
        gload16(gB1 + 128, ldsb + 65536 + 24576 + woff);
    }
    BOUNDARY(8);        // tile 0 ready; tiles 1,2 in flight

#pragma unroll 1
    for (int t = 0; t < 125; ++t) {       // stages tiles 3..127
        TILEBODY(t, 1);
        BOUNDARY(8);                      // t+1 ready; t+2, t+3 in flight
    }
    TILEBODY(125, 0);
    BOUNDARY(4);                          // 126 ready; 127 in flight
    TILEBODY(126, 0);
    BOUNDARY(0);                          // 127 ready (final drain)
    TILEBODY(127, 0);

    // ---- fused epilogue (bf16 x/avg from Gin; C/D: col=l&15, row=(l>>4)*4+r)
#pragma unroll
    for (int mi = 0; mi < 8; ++mi) {
        long rbase = m0 + wm * 128 + mi * 16 + (l >> 4) * 4;
#pragma unroll
        for (int nj = 0; nj < 2; ++nj) {
            int d = n0 + wn * 32 + nj * 16 + lm;
            float bi_ = bias[d];
            float bf_ = bias[d + 2048];
#pragma unroll
            for (int r = 0; r < 4; ++r) {
                long row = rbase + r;
                unsigned int ux = Gin[row * 4096 + d];
                unsigned int ua = Gin[row * 4096 + 2048 + d];
                union { unsigned int u; float f; } cx, ca;
                cx.u = ux << 16; ca.u = ua << 16;
                float gi = acc[mi][nj][r] + bi_;
                float gf = acc[mi][nj + 2][r] + bf_;
                float si = 1.f / (1.f + __expf(-gi));
                float sf = 1.f / (1.f + __expf(-gf));
                OUT[row * 2048 + d] = si * cx.f + sf * ca.f;
            }
        }
    }
}

extern "C" void kernel_launch(void* const* d_in, const int* in_sizes, int n_in,
                              void* d_out, int out_size, void* d_ws, size_t ws_size,
                              hipStream_t stream) {
    const float* X = (const float*)d_in[0];     // layer_in [8][2048][2048]
    const float* W = (const float*)d_in[1];     // W_gate [4096][4096]
    const float* bias = (const float*)d_in[2];  // b_gate [4096]

    float* OUT = (float*)d_out;                 // gating_out
    float* AVG = OUT + (long)Mm * Dd;           // average_out

    char* ws = (char*)d_ws;
    unsigned short* Wb  = (unsigned short*)ws;                    // 33,554,432 B
    unsigned short* Gin = (unsigned short*)(ws + 33554432);       // 134,217,728 B
    float* S = (float*)(ws + 33554432 + 134217728);               // 2,097,152 B

    wconv_kernel<<<2048, 256, 0, stream>>>(W, Wb, (long)Kk * Kk);
    ksum_kernel<<<dim3(Bb * NC, Dd / 256), 256, 0, stream>>>(X, S);
    kscan_kernel<<<dim3(Bb * NC, Dd / 256), 256, 0, stream>>>(X, S, AVG, Gin);
    gemm2p_kernel<<<1024, 512, 0, stream>>>(Gin, Wb, bias, OUT);
}

// Round 7
// 615.574 us; speedup vs baseline: 1.6221x; 1.0311x over previous
//
#include <hip/hip_runtime.h>
#include <hip/hip_bf16.h>

// B=8, T=2048, D=2048.
//   avg = cumsum(x, axis=T) / (t+1)
//   gates = concat(x, avg) @ W^T + b    (W: [4096][4096])
//   out0 = sig(gates[:, :2048]) * x + sig(gates[:, 2048:]) * avg
// outputs: [out0 fp32] ++ [avg fp32]

#define Bb 8
#define Tt 2048
#define Dd 2048
#define Mm (Bb * Tt)       // 16384
#define Kk 4096
#define NC 32
#define CT 64

typedef __bf16 bf16x8 __attribute__((ext_vector_type(8)));
typedef float f32x4 __attribute__((ext_vector_type(4)));

__device__ __forceinline__ void gload16(const void* g, void* l) {
    __builtin_amdgcn_global_load_lds(
        (const __attribute__((address_space(1))) unsigned int*)g,
        (__attribute__((address_space(3))) unsigned int*)l, 16, 0, 0);
}

// ---------------- K1: W fp32 -> bf16 ----------------
__global__ void wconv_kernel(const float* __restrict__ W,
                             unsigned short* __restrict__ Wb, long n) {
    long i = ((long)blockIdx.x * blockDim.x + threadIdx.x) * 4;
    long stride = (long)gridDim.x * blockDim.x * 4;
    for (; i < n; i += stride) {
        float4 v = *(const float4*)(W + i);
        __hip_bfloat16 a = __float2bfloat16(v.x);
        __hip_bfloat16 b = __float2bfloat16(v.y);
        __hip_bfloat16 c = __float2bfloat16(v.z);
        __hip_bfloat16 d = __float2bfloat16(v.w);
        ushort4 u;
        u.x = *(unsigned short*)&a; u.y = *(unsigned short*)&b;
        u.z = *(unsigned short*)&c; u.w = *(unsigned short*)&d;
        *(ushort4*)(Wb + i) = u;
    }
}

// ---------------- K2: per-chunk sums ----------------
__global__ void ksum_kernel(const float* __restrict__ X, float* __restrict__ S) {
    int d = blockIdx.y * 256 + threadIdx.x;
    int bc = blockIdx.x;
    int b = bc >> 5, c = bc & 31;
    const float* p = X + ((long)(b * Tt + c * CT)) * Dd + d;
    float s = 0.f;
#pragma unroll 8
    for (int t = 0; t < CT; ++t) s += p[(long)t * Dd];
    S[(long)bc * Dd + d] = s;
}

// ---------------- K3: scan + emit avg fp32 + gating_in bf16 ----------------
__global__ void kscan_kernel(const float* __restrict__ X, const float* __restrict__ S,
                             float* __restrict__ AVG, unsigned short* __restrict__ Gin) {
    int d = blockIdx.y * 256 + threadIdx.x;
    int bc = blockIdx.x;
    int b = bc >> 5, c = bc & 31;
    const float* Sp = S + (long)(b * NC) * Dd + d;
    float run = 0.f;
    for (int cc = 0; cc < c; ++cc) run += Sp[(long)cc * Dd];
    const float* p = X + ((long)(b * Tt + c * CT)) * Dd + d;
    long row = (long)b * Tt + c * CT;
    for (int tt = 0; tt < CT; ++tt) {
        float x = p[(long)tt * Dd];
        run += x;
        float av = run / (float)(c * CT + tt + 1);
        long r = row + tt;
        AVG[r * Dd + d] = av;
        __hip_bfloat16 xb = __float2bfloat16(x);
        __hip_bfloat16 ab = __float2bfloat16(av);
        Gin[r * 4096 + d] = *(unsigned short*)&xb;
        Gin[r * 4096 + 2048 + d] = *(unsigned short*)&ab;
    }
}

// ---------------- K4: 8-wave 256x(128d x 2 gates), BK=64, 4-phase tiles -----
// m201-faithful: 2-buf (2 x 64KB), per-phase {ds_reads + 2 gload_lds chunk ->
// barrier -> lgkmcnt(0) -> setprio 16xMFMA -> barrier}; counted vmcnt(4) at
// PH1/PH3 ends only (never 0 in main loop). 64 K-tiles (half the boundaries
// of BK=32). Proven 0-conflict chunk-XOR swizzle (pre-swizzled global source,
// linear LDS dest via global_load_lds).
// Buf layout (64KB): [A kk0 16K][B kk0 16K][A kk1 16K][B kk1 16K].
// Steady-state FIFO at PH1-end: {A1(t),B1(t), A0(t+1),B0(t+1)} -> vmcnt(4)
// completes A1(t),B1(t) (needed by PH2/PH3). At PH3-end: {A0..B1(t+1)} x8
// -> vmcnt(4) completes A0(t+1),B0(t+1) (needed by next PH0/PH1).
#define MFMA(va, vb, c_) c_ = __builtin_amdgcn_mfma_f32_16x16x32_bf16(va, vb, c_, 0, 0, 0)
#define RD(p_, i_) (*(const bf16x8*)((p_) + (i_) * 1024))
#define SBAR __builtin_amdgcn_s_barrier()
#define SCHB __builtin_amdgcn_sched_barrier(0)
#define LGKM0 asm volatile("s_waitcnt lgkmcnt(0)" ::: "memory")

#define CL_LO(A0_, A1_, A2_, A3_, B0_, B1_, B2_, B3_)                           \
    __builtin_amdgcn_s_setprio(1);                                              \
    MFMA(A0_,B0_,acc[0][0]); MFMA(A0_,B1_,acc[0][1]); MFMA(A0_,B2_,acc[0][2]); MFMA(A0_,B3_,acc[0][3]); \
    MFMA(A1_,B0_,acc[1][0]); MFMA(A1_,B1_,acc[1][1]); MFMA(A1_,B2_,acc[1][2]); MFMA(A1_,B3_,acc[1][3]); \
    MFMA(A2_,B0_,acc[2][0]); MFMA(A2_,B1_,acc[2][1]); MFMA(A2_,B2_,acc[2][2]); MFMA(A2_,B3_,acc[2][3]); \
    MFMA(A3_,B0_,acc[3][0]); MFMA(A3_,B1_,acc[3][1]); MFMA(A3_,B2_,acc[3][2]); MFMA(A3_,B3_,acc[3][3]); \
    __builtin_amdgcn_s_setprio(0);
#define CL_HI(A4_, A5_, A6_, A7_, B0_, B1_, B2_, B3_)                           \
    __builtin_amdgcn_s_setprio(1);                                              \
    MFMA(A4_,B0_,acc[4][0]); MFMA(A4_,B1_,acc[4][1]); MFMA(A4_,B2_,acc[4][2]); MFMA(A4_,B3_,acc[4][3]); \
    MFMA(A5_,B0_,acc[5][0]); MFMA(A5_,B1_,acc[5][1]); MFMA(A5_,B2_,acc[5][2]); MFMA(A5_,B3_,acc[5][3]); \
    MFMA(A6_,B0_,acc[6][0]); MFMA(A6_,B1_,acc[6][1]); MFMA(A6_,B2_,acc[6][2]); MFMA(A6_,B3_,acc[6][3]); \
    MFMA(A7_,B0_,acc[7][0]); MFMA(A7_,B1_,acc[7][1]); MFMA(A7_,B2_,acc[7][2]); MFMA(A7_,B3_,acc[7][3]); \
    __builtin_amdgcn_s_setprio(0);

#define TILE64(t_, bb_, STG_, V1_, V3_)                                         \
  {                                                                             \
    const char* pa_ = rA0 + (bb_);                                              \
    const char* pb_ = rB0 + (bb_);                                              \
    char* nb_ = ldsb + ((bb_) ^ 65536) + woff;                                  \
    const long ko_ = ((long)(t_) + 1) * 128;                                    \
    /* -- PH0: reads A mi0-3 kk0 + B kk0; stage A0(t+1); MFMA lo kk0 -- */      \
    bf16x8 a0 = RD(pa_,0), a1 = RD(pa_,1), a2 = RD(pa_,2), a3 = RD(pa_,3);      \
    bf16x8 b0 = RD(pb_,0), b1 = RD(pb_,1), b2 = RD(pb_,2), b3 = RD(pb_,3);      \
    if (STG_) { gload16(gA0 + ko_, nb_); gload16(gA1 + ko_, nb_ + 8192); }      \
    SCHB; SBAR; LGKM0; SCHB;                                                    \
    CL_LO(a0, a1, a2, a3, b0, b1, b2, b3)                                       \
    SCHB; SBAR;                                                                 \
    /* -- PH1: reads A mi4-7 kk0; stage B0(t+1); MFMA hi kk0; vmcnt(V1) -- */   \
    bf16x8 a4 = RD(pa_,4), a5 = RD(pa_,5), a6 = RD(pa_,6), a7 = RD(pa_,7);      \
    if (STG_) { gload16(gB0 + ko_, nb_ + 16384); gload16(gB1 + ko_, nb_ + 24576); } \
    SCHB; SBAR; LGKM0; SCHB;                                                    \
    CL_HI(a4, a5, a6, a7, b0, b1, b2, b3)                                       \
    SCHB;                                                                       \
    asm volatile("s_waitcnt vmcnt(" #V1_ ")" ::: "memory");                     \
    SBAR;                                                                       \
    /* -- PH2: reads A mi0-3 kk1 + B kk1; stage A1(t+1); MFMA lo kk1 -- */      \
    bf16x8 c0 = RD(pa_+32768,0), c1 = RD(pa_+32768,1), c2 = RD(pa_+32768,2), c3 = RD(pa_+32768,3); \
    bf16x8 d0 = RD(pb_+32768,0), d1 = RD(pb_+32768,1), d2 = RD(pb_+32768,2), d3 = RD(pb_+32768,3); \
    if (STG_) { gload16(gA0 + ko_ + 64, nb_ + 32768); gload16(gA1 + ko_ + 64, nb_ + 40960); } \
    SCHB; SBAR; LGKM0; SCHB;                                                    \
    CL_LO(c0, c1, c2, c3, d0, d1, d2, d3)                                       \
    SCHB; SBAR;                                                                 \
    /* -- PH3: reads A mi4-7 kk1; stage B1(t+1); MFMA hi kk1; vmcnt(V3) -- */   \
    bf16x8 c4 = RD(pa_+32768,4), c5 = RD(pa_+32768,5), c6 = RD(pa_+32768,6), c7 = RD(pa_+32768,7); \
    if (STG_) { gload16(gB0 + ko_ + 64, nb_ + 49152); gload16(gB1 + ko_ + 64, nb_ + 57344); } \
    SCHB; SBAR; LGKM0; SCHB;                                                    \
    CL_HI(c4, c5, c6, c7, d0, d1, d2, d3)                                       \
    SCHB;                                                                       \
    asm volatile("s_waitcnt vmcnt(" #V3_ ")" ::: "memory");                     \
    SBAR;                                                                       \
  }

__global__ __launch_bounds__(512, 1) void gemm64_kernel(
    const unsigned short* __restrict__ Gin,  // [16384][4096] bf16
    const unsigned short* __restrict__ Wb,   // [4096][4096] bf16
    const float* __restrict__ bias,          // [4096]
    float* __restrict__ OUT)                 // [16384][2048]
{
    __shared__ __attribute__((aligned(128))) char lds[131072]; // 2 x 64KB
    char* ldsb = (char*)lds;

    const int tid = threadIdx.x;
    const int w = tid >> 6, l = tid & 63;
    const int wm = w >> 2, wn = w & 3;       // 2(M) x 4(N) waves
    const int lm = l & 15;
    const int woff = w * 1024;

    // Batch-aware mapping (FETCH-proven): 256-block rounds = 16 m-tiles x
    // 16 n-tiles (A 32MB + W 32MB < L3); per XCD 2 n-tiles (B panel -> L2).
    const int bid = blockIdx.x;
    const int batch = bid >> 8;
    const int rr = bid & 255;
    const int xcd = rr & 7;
    const int j = rr >> 3;
    const int nt = xcd * 2 + (j >> 4);
    const int mt = batch * 16 + (j & 15);
    const long m0 = (long)mt * 256;
    const int n0 = nt * 128;

    // ---- staging addresses (pre-swizzled global chunk; LDS dest linear) ----
    const int srow = tid >> 2;
    const int schunk = (tid & 3) ^ ((tid >> 3) & 3);
    const char* gA0 = (const char*)Gin + (m0 + srow) * 8192 + schunk * 16;
    const char* gA1 = gA0 + 128 * 8192;
    // B tile row j (0..255) -> W row: d-block (j>>6)*32 + (j&31), gate (j>>5)&1
    const long jr0 = n0 + ((srow >> 6) << 5) + (srow & 31) + (((srow >> 5) & 1) << 11);
    const int j1 = 128 + srow;
    const long jr1 = n0 + ((j1 >> 6) << 5) + (j1 & 31) + (((j1 >> 5) & 1) << 11);
    const char* gB0 = (const char*)Wb + jr0 * 8192 + schunk * 16;
    const char* gB1 = (const char*)Wb + jr1 * 8192 + schunk * 16;

    // ---- read addresses (proven 0-conflict swizzle) ----
    const int cbyte = (((l >> 4) ^ ((lm >> 1) & 3))) * 16;
    const char* rA0 = ldsb + (wm * 128 + lm) * 64 + cbyte;          // +bb +kk*32768 +mi*1024
    const char* rB0 = ldsb + 16384 + (wn * 64 + lm) * 64 + cbyte;   // +bb +kk*32768 +nj*1024

    f32x4 acc[8][4] = {};   // [mi][nj]: nj 0-1 gate-i, 2-3 gate-f

    // prologue: stage tile 0 (A0,B0,A1,B1) into buf0
    gload16(gA0,      ldsb + woff);
    gload16(gA1,      ldsb + 8192 + woff);
    gload16(gB0,      ldsb + 16384 + woff);
    gload16(gB1,      ldsb + 24576 + woff);
    gload16(gA0 + 64, ldsb + 32768 + woff);
    gload16(gA1 + 64, ldsb + 40960 + woff);
    gload16(gB0 + 64, ldsb + 49152 + woff);
    gload16(gB1 + 64, ldsb + 57344 + woff);
    asm volatile("s_waitcnt vmcnt(4)" ::: "memory");   // A0,B0 landed; A1,B1 in flight
    SBAR; SCHB;

#pragma unroll 1
    for (int t = 0; t < 62; t += 2) {     // t = 0..61, stages tiles 1..62
        TILE64(t,     0,     1, 4, 4)
        TILE64(t + 1, 65536, 1, 4, 4)
    }
    TILE64(62, 0,     1, 4, 4)            // stages tile 63
    TILE64(63, 65536, 0, 0, 0)            // tail: drain

    // ---- fused epilogue (bf16 x/avg from Gin; C/D: col=l&15, row=(l>>4)*4+r)
#pragma unroll
    for (int mi = 0; mi < 8; ++mi) {
        long rbase = m0 + wm * 128 + mi * 16 + (l >> 4) * 4;
#pragma unroll
        for (int nj = 0; nj < 2; ++nj) {
            int d = n0 + wn * 32 + nj * 16 + lm;
            float bi_ = bias[d];
            float bf_ = bias[d + 2048];
#pragma unroll
            for (int r = 0; r < 4; ++r) {
                long row = rbase + r;
                unsigned int ux = Gin[row * 4096 + d];
                unsigned int ua = Gin[row * 4096 + 2048 + d];
                union { unsigned int u; float f; } cx, ca;
                cx.u = ux << 16; ca.u = ua << 16;
                float gi = acc[mi][nj][r] + bi_;
                float gf = acc[mi][nj + 2][r] + bf_;
                float si = 1.f / (1.f + __expf(-gi));
                float sf = 1.f / (1.f + __expf(-gf));
                OUT[row * 2048 + d] = si * cx.f + sf * ca.f;
            }
        }
    }
}

extern "C" void kernel_launch(void* const* d_in, const int* in_sizes, int n_in,
                              void* d_out, int out_size, void* d_ws, size_t ws_size,
                              hipStream_t stream) {
    const float* X = (const float*)d_in[0];     // layer_in [8][2048][2048]
    const float* W = (const float*)d_in[1];     // W_gate [4096][4096]
    const float* bias = (const float*)d_in[2];  // b_gate [4096]

    float* OUT = (float*)d_out;                 // gating_out
    float* AVG = OUT + (long)Mm * Dd;           // average_out

    char* ws = (char*)d_ws;
    unsigned short* Wb  = (unsigned short*)ws;                    // 33,554,432 B
    unsigned short* Gin = (unsigned short*)(ws + 33554432);       // 134,217,728 B
    float* S = (float*)(ws + 33554432 + 134217728);               // 2,097,152 B

    wconv_kernel<<<2048, 256, 0, stream>>>(W, Wb, (long)Kk * Kk);
    ksum_kernel<<<dim3(Bb * NC, Dd / 256), 256, 0, stream>>>(X, S);
    kscan_kernel<<<dim3(Bb * NC, Dd / 256), 256, 0, stream>>>(X, S, AVG, Gin);
    gemm64_kernel<<<1024, 512, 0, stream>>>(Gin, Wb, bias, OUT);
}

// Round 8
// 609.656 us; speedup vs baseline: 1.6379x; 1.0097x over previous
//
#include <hip/hip_runtime.h>
#include <hip/hip_bf16.h>

// B=8, T=2048, D=2048.
//   avg = cumsum(x, axis=T) / (t+1)
//   gates = concat(x, avg) @ W^T + b    (W: [4096][4096])
//   out0 = sig(gates[:, :2048]) * x + sig(gates[:, 2048:]) * avg
// outputs: [out0 fp32] ++ [avg fp32]

#define Bb 8
#define Tt 2048
#define Dd 2048
#define Mm (Bb * Tt)       // 16384
#define Kk 4096
#define NC 32
#define CT 64

typedef __bf16 bf16x8 __attribute__((ext_vector_type(8)));
typedef float f32x4 __attribute__((ext_vector_type(4)));

__device__ __forceinline__ void gload16(const void* g, void* l) {
    __builtin_amdgcn_global_load_lds(
        (const __attribute__((address_space(1))) unsigned int*)g,
        (__attribute__((address_space(3))) unsigned int*)l, 16, 0, 0);
}

// ---------------- K1: W fp32 -> bf16 ----------------
__global__ void wconv_kernel(const float* __restrict__ W,
                             unsigned short* __restrict__ Wb, long n) {
    long i = ((long)blockIdx.x * blockDim.x + threadIdx.x) * 4;
    long stride = (long)gridDim.x * blockDim.x * 4;
    for (; i < n; i += stride) {
        float4 v = *(const float4*)(W + i);
        __hip_bfloat16 a = __float2bfloat16(v.x);
        __hip_bfloat16 b = __float2bfloat16(v.y);
        __hip_bfloat16 c = __float2bfloat16(v.z);
        __hip_bfloat16 d = __float2bfloat16(v.w);
        ushort4 u;
        u.x = *(unsigned short*)&a; u.y = *(unsigned short*)&b;
        u.z = *(unsigned short*)&c; u.w = *(unsigned short*)&d;
        *(ushort4*)(Wb + i) = u;
    }
}

// ---------------- K2: per-chunk sums ----------------
__global__ void ksum_kernel(const float* __restrict__ X, float* __restrict__ S) {
    int d = blockIdx.y * 256 + threadIdx.x;
    int bc = blockIdx.x;
    int b = bc >> 5, c = bc & 31;
    const float* p = X + ((long)(b * Tt + c * CT)) * Dd + d;
    float s = 0.f;
#pragma unroll 8
    for (int t = 0; t < CT; ++t) s += p[(long)t * Dd];
    S[(long)bc * Dd + d] = s;
}

// ---------------- K3: scan + emit avg fp32 + gating_in bf16 ----------------
__global__ void kscan_kernel(const float* __restrict__ X, const float* __restrict__ S,
                             float* __restrict__ AVG, unsigned short* __restrict__ Gin) {
    int d = blockIdx.y * 256 + threadIdx.x;
    int bc = blockIdx.x;
    int b = bc >> 5, c = bc & 31;
    const float* Sp = S + (long)(b * NC) * Dd + d;
    float run = 0.f;
    for (int cc = 0; cc < c; ++cc) run += Sp[(long)cc * Dd];
    const float* p = X + ((long)(b * Tt + c * CT)) * Dd + d;
    long row = (long)b * Tt + c * CT;
    for (int tt = 0; tt < CT; ++tt) {
        float x = p[(long)tt * Dd];
        run += x;
        float av = run / (float)(c * CT + tt + 1);
        long r = row + tt;
        AVG[r * Dd + d] = av;
        __hip_bfloat16 xb = __float2bfloat16(x);
        __hip_bfloat16 ab = __float2bfloat16(av);
        Gin[r * 4096 + d] = *(unsigned short*)&xb;
        Gin[r * 4096 + 2048 + d] = *(unsigned short*)&ab;
    }
}

// ---------------- K4: 8-wave 256x(128d x 2 gates), BK=64, pipelined reads ---
// vs R7: ds_reads for phase p+1 issue BEFORE phase p's MFMA cluster, so the
// DS pipe services them under the matrix pipe (breaking the read->MFMA
// lockstep that capped MfmaUtil at ~50%). Only 2 barriers/tile:
//   mid-tile  vmcnt(2)+barrier : kk1(t) staging visible before its reads
//   boundary  vmcnt(4)+barrier : kk0(t+1) visible; never drain to 0 in loop.
// vm FIFO invariant at tile entry: [Akk1(t)x2, Bkk1(t)x2] outstanding.
// Registers rotate in place: aL/aH reused across kk halves (WAR safe by
// program order), B has two sets bb (kk0) / bd (kk1). ~220 VGPR, 2 waves/SIMD.
#define MFMA(va, vb, c_) c_ = __builtin_amdgcn_mfma_f32_16x16x32_bf16(va, vb, c_, 0, 0, 0)
#define RD(p_, i_) (*(const bf16x8*)((p_) + (i_) * 1024))
#define SBAR __builtin_amdgcn_s_barrier()
#define SCHB __builtin_amdgcn_sched_barrier(0)
#define LGKM0 do { asm volatile("s_waitcnt lgkmcnt(0)" ::: "memory"); SCHB; } while (0)

#define CL_LO(B0_, B1_, B2_, B3_)                                               \
    __builtin_amdgcn_s_setprio(1);                                              \
    MFMA(aL0,B0_,acc[0][0]); MFMA(aL0,B1_,acc[0][1]); MFMA(aL0,B2_,acc[0][2]); MFMA(aL0,B3_,acc[0][3]); \
    MFMA(aL1,B0_,acc[1][0]); MFMA(aL1,B1_,acc[1][1]); MFMA(aL1,B2_,acc[1][2]); MFMA(aL1,B3_,acc[1][3]); \
    MFMA(aL2,B0_,acc[2][0]); MFMA(aL2,B1_,acc[2][1]); MFMA(aL2,B2_,acc[2][2]); MFMA(aL2,B3_,acc[2][3]); \
    MFMA(aL3,B0_,acc[3][0]); MFMA(aL3,B1_,acc[3][1]); MFMA(aL3,B2_,acc[3][2]); MFMA(aL3,B3_,acc[3][3]); \
    __builtin_amdgcn_s_setprio(0);
#define CL_HI(B0_, B1_, B2_, B3_)                                               \
    __builtin_amdgcn_s_setprio(1);                                              \
    MFMA(aH0,B0_,acc[4][0]); MFMA(aH0,B1_,acc[4][1]); MFMA(aH0,B2_,acc[4][2]); MFMA(aH0,B3_,acc[4][3]); \
    MFMA(aH1,B0_,acc[5][0]); MFMA(aH1,B1_,acc[5][1]); MFMA(aH1,B2_,acc[5][2]); MFMA(aH1,B3_,acc[5][3]); \
    MFMA(aH2,B0_,acc[6][0]); MFMA(aH2,B1_,acc[6][1]); MFMA(aH2,B2_,acc[6][2]); MFMA(aH2,B3_,acc[6][3]); \
    MFMA(aH3,B0_,acc[7][0]); MFMA(aH3,B1_,acc[7][1]); MFMA(aH3,B2_,acc[7][2]); MFMA(aH3,B3_,acc[7][3]); \
    __builtin_amdgcn_s_setprio(0);

#define TILE64(t_, bb_, STG_, VM_, VB_)                                         \
  {                                                                             \
    const char* pa_ = rA0 + (bb_);                                              \
    const char* pb_ = rB0 + (bb_);                                              \
    char* nb_ = ldsb + ((bb_) ^ 65536) + woff;                                  \
    const long ko_ = ((long)(t_) + 1) * 128;                                    \
    /* tile start: X = kk0 lo-A + kk0 B; stage Akk0(t+1) */                     \
    aL0 = RD(pa_,0); aL1 = RD(pa_,1); aL2 = RD(pa_,2); aL3 = RD(pa_,3);         \
    bb0 = RD(pb_,0); bb1 = RD(pb_,1); bb2 = RD(pb_,2); bb3 = RD(pb_,3);         \
    if (STG_) { gload16(gA0 + ko_, nb_); gload16(gA1 + ko_, nb_ + 8192); }      \
    LGKM0;                                      /* X ready */                   \
    /* PH0: issue Y = kk0 hi-A; MFMA lo-kk0 */                                  \
    aH0 = RD(pa_,4); aH1 = RD(pa_,5); aH2 = RD(pa_,6); aH3 = RD(pa_,7);         \
    SCHB;                                                                       \
    CL_LO(bb0, bb1, bb2, bb3)                                                   \
    SCHB;                                                                       \
    asm volatile("s_waitcnt vmcnt(" #VM_ ")" ::: "memory");                     \
    SBAR; SCHB;                                 /* kk1(t) visible */            \
    LGKM0;                                      /* Y ready */                   \
    /* PH1: issue Z = kk1 lo-A + kk1 B; stage Bkk0(t+1); MFMA hi-kk0 */         \
    aL0 = RD(pa_+32768,0); aL1 = RD(pa_+32768,1); aL2 = RD(pa_+32768,2); aL3 = RD(pa_+32768,3); \
    bd0 = RD(pb_+32768,0); bd1 = RD(pb_+32768,1); bd2 = RD(pb_+32768,2); bd3 = RD(pb_+32768,3); \
    if (STG_) { gload16(gB0 + ko_, nb_ + 16384); gload16(gB1 + ko_, nb_ + 24576); } \
    SCHB;                                                                       \
    CL_HI(bb0, bb1, bb2, bb3)                                                   \
    SCHB;                                                                       \
    LGKM0;                                      /* Z ready */                   \
    /* PH2: issue W = kk1 hi-A; stage Akk1(t+1); MFMA lo-kk1 */                 \
    aH0 = RD(pa_+32768,4); aH1 = RD(pa_+32768,5); aH2 = RD(pa_+32768,6); aH3 = RD(pa_+32768,7); \
    if (STG_) { gload16(gA0 + ko_ + 64, nb_ + 32768); gload16(gA1 + ko_ + 64, nb_ + 40960); } \
    SCHB;                                                                       \
    CL_LO(bd0, bd1, bd2, bd3)                                                   \
    SCHB;                                                                       \
    LGKM0;                                      /* W ready */                   \
    /* PH3: stage Bkk1(t+1); MFMA hi-kk1 */                                     \
    if (STG_) { gload16(gB0 + ko_ + 64, nb_ + 49152); gload16(gB1 + ko_ + 64, nb_ + 57344); } \
    SCHB;                                                                       \
    CL_HI(bd0, bd1, bd2, bd3)                                                   \
    SCHB;                                                                       \
    asm volatile("s_waitcnt vmcnt(" #VB_ ")" ::: "memory");                     \
    SBAR; SCHB;                                 /* kk0(t+1) visible */          \
  }

__global__ __launch_bounds__(512, 1) void gemmsp_kernel(
    const unsigned short* __restrict__ Gin,  // [16384][4096] bf16
    const unsigned short* __restrict__ Wb,   // [4096][4096] bf16
    const float* __restrict__ bias,          // [4096]
    float* __restrict__ OUT)                 // [16384][2048]
{
    __shared__ __attribute__((aligned(128))) char lds[131072]; // 2 x 64KB
    char* ldsb = (char*)lds;

    const int tid = threadIdx.x;
    const int w = tid >> 6, l = tid & 63;
    const int wm = w >> 2, wn = w & 3;       // 2(M) x 4(N) waves
    const int lm = l & 15;
    const int woff = w * 1024;

    // Batch-aware mapping (FETCH-proven): 256-block rounds = 16 m-tiles x
    // 16 n-tiles (A 32MB + W 32MB < L3); per XCD 2 n-tiles (B panel -> L2).
    const int bid = blockIdx.x;
    const int batch = bid >> 8;
    const int rr = bid & 255;
    const int xcd = rr & 7;
    const int j = rr >> 3;
    const int nt = xcd * 2 + (j >> 4);
    const int mt = batch * 16 + (j & 15);
    const long m0 = (long)mt * 256;
    const int n0 = nt * 128;

    // ---- staging addresses (pre-swizzled global chunk; LDS dest linear) ----
    const int srow = tid >> 2;
    const int schunk = (tid & 3) ^ ((tid >> 3) & 3);
    const char* gA0 = (const char*)Gin + (m0 + srow) * 8192 + schunk * 16;
    const char* gA1 = gA0 + 128 * 8192;
    // B tile row j (0..255) -> W row: d-block (j>>6)*32 + (j&31), gate (j>>5)&1
    const long jr0 = n0 + ((srow >> 6) << 5) + (srow & 31) + (((srow >> 5) & 1) << 11);
    const int j1 = 128 + srow;
    const long jr1 = n0 + ((j1 >> 6) << 5) + (j1 & 31) + (((j1 >> 5) & 1) << 11);
    const char* gB0 = (const char*)Wb + jr0 * 8192 + schunk * 16;
    const char* gB1 = (const char*)Wb + jr1 * 8192 + schunk * 16;

    // ---- read addresses (proven 0-conflict swizzle) ----
    const int cbyte = (((l >> 4) ^ ((lm >> 1) & 3))) * 16;
    const char* rA0 = ldsb + (wm * 128 + lm) * 64 + cbyte;          // +bb +kk*32768 +mi*1024
    const char* rB0 = ldsb + 16384 + (wn * 64 + lm) * 64 + cbyte;   // +bb +kk*32768 +nj*1024

    f32x4 acc[8][4] = {};   // [mi][nj]: nj 0-1 gate-i, 2-3 gate-f

    // rotating operand registers
    bf16x8 aL0, aL1, aL2, aL3, aH0, aH1, aH2, aH3;
    bf16x8 bb0, bb1, bb2, bb3, bd0, bd1, bd2, bd3;

    // prologue: stage tile 0 (Akk0, Bkk0, Akk1, Bkk1) into buf0
    gload16(gA0,      ldsb + woff);
    gload16(gA1,      ldsb + 8192 + woff);
    gload16(gB0,      ldsb + 16384 + woff);
    gload16(gB1,      ldsb + 24576 + woff);
    gload16(gA0 + 64, ldsb + 32768 + woff);
    gload16(gA1 + 64, ldsb + 40960 + woff);
    gload16(gB0 + 64, ldsb + 49152 + woff);
    gload16(gB1 + 64, ldsb + 57344 + woff);
    asm volatile("s_waitcnt vmcnt(4)" ::: "memory");   // kk0 landed; kk1 in flight
    SBAR; SCHB;

#pragma unroll 1
    for (int t = 0; t < 62; t += 2) {     // stages tiles 1..62
        TILE64(t,     0,     1, 2, 4)
        TILE64(t + 1, 65536, 1, 2, 4)
    }
    TILE64(62, 0,     1, 2, 4)            // stages tile 63
    TILE64(63, 65536, 0, 0, 0)            // tail: drain

    // ---- fused epilogue (bf16 x/avg from Gin; C/D: col=l&15, row=(l>>4)*4+r)
#pragma unroll
    for (int mi = 0; mi < 8; ++mi) {
        long rbase = m0 + wm * 128 + mi * 16 + (l >> 4) * 4;
#pragma unroll
        for (int nj = 0; nj < 2; ++nj) {
            int d = n0 + wn * 32 + nj * 16 + lm;
            float bi_ = bias[d];
            float bf_ = bias[d + 2048];
#pragma unroll
            for (int r = 0; r < 4; ++r) {
                long row = rbase + r;
                unsigned int ux = Gin[row * 4096 + d];
                unsigned int ua = Gin[row * 4096 + 2048 + d];
                union { unsigned int u; float f; } cx, ca;
                cx.u = ux << 16; ca.u = ua << 16;
                float gi = acc[mi][nj][r] + bi_;
                float gf = acc[mi][nj + 2][r] + bf_;
                float si = 1.f / (1.f + __expf(-gi));
                float sf = 1.f / (1.f + __expf(-gf));
                OUT[row * 2048 + d] = si * cx.f + sf * ca.f;
            }
        }
    }
}

extern "C" void kernel_launch(void* const* d_in, const int* in_sizes, int n_in,
                              void* d_out, int out_size, void* d_ws, size_t ws_size,
                              hipStream_t stream) {
    const float* X = (const float*)d_in[0];     // layer_in [8][2048][2048]
    const float* W = (const float*)d_in[1];     // W_gate [4096][4096]
    const float* bias = (const float*)d_in[2];  // b_gate [4096]

    float* OUT = (float*)d_out;                 // gating_out
    float* AVG = OUT + (long)Mm * Dd;           // average_out

    char* ws = (char*)d_ws;
    unsigned short* Wb  = (unsigned short*)ws;                    // 33,554,432 B
    unsigned short* Gin = (unsigned short*)(ws + 33554432);       // 134,217,728 B
    float* S = (float*)(ws + 33554432 + 134217728);               // 2,097,152 B

    wconv_kernel<<<2048, 256, 0, stream>>>(W, Wb, (long)Kk * Kk);
    ksum_kernel<<<dim3(Bb * NC, Dd / 256), 256, 0, stream>>>(X, S);
    kscan_kernel<<<dim3(Bb * NC, Dd / 256), 256, 0, stream>>>(X, S, AVG, Gin);
    gemmsp_kernel<<<1024, 512, 0, stream>>>(Gin, Wb, bias, OUT);
}